// Round 1
// baseline (310.377 us; speedup 1.0000x reference)
//
#include <hip/hip_runtime.h>
#include <math.h>

#define H_FM 200
#define W_FM 304
#define C_FM 256
#define CROP 14
#define PH 7

// One wave (64 threads) per output position (n, py, px).
// Thread t handles channels [4t, 4t+4) via float4 -> each neighbor fetch is a
// fully coalesced 1 KB wave-level read (NHWC, channels innermost).
__global__ __launch_bounds__(64) void roi_pool_kernel(
    const float* __restrict__ fm,         // [200, 304, 256]
    const float* __restrict__ proposals,  // [N, 4]  (x1, y1, x2, y2) in image coords
    const int*   __restrict__ image_shape,// [2] (H_img, W_img)
    float*       __restrict__ out,        // [N, 7, 7, 256]
    int N)
{
    const int bid = blockIdx.x;
    const int n   = bid / (PH * PH);
    const int pos = bid % (PH * PH);
    const int py  = pos / PH;
    const int px  = pos % PH;
    const int tid = threadIdx.x;          // 0..63

    const float himg = (float)image_shape[0];
    const float wimg = (float)image_shape[1];

    const float bx1 = proposals[n * 4 + 0] / wimg;
    const float by1 = proposals[n * 4 + 1] / himg;
    const float bx2 = proposals[n * 4 + 2] / wimg;
    const float by2 = proposals[n * 4 + 3] / himg;

    const float Hm1 = (float)(H_FM - 1);
    const float Wm1 = (float)(W_FM - 1);

    // Matches reference: ys = y1*(H-1) + i * ((y2-y1)*(H-1)/(crop-1))
    const float ybase = by1 * Hm1;
    const float xbase = bx1 * Wm1;
    const float ystep = (by2 - by1) * Hm1 / (float)(CROP - 1);
    const float xstep = (bx2 - bx1) * Wm1 / (float)(CROP - 1);

    const int iy0 = 2 * py;
    const int ix0 = 2 * px;

    const float* fmc = fm + (size_t)tid * 4;   // this thread's channel slice

    float4 result = make_float4(-INFINITY, -INFINITY, -INFINITY, -INFINITY);

    #pragma unroll
    for (int a = 0; a < 2; ++a) {
        const float ysv = ybase + (float)(iy0 + a) * ystep;
        const float y0f = floorf(ysv);
        const float ly  = ysv - y0f;
        int y0 = (int)y0f;
        y0 = min(max(y0, 0), H_FM - 1);
        const int y1c = min(y0 + 1, H_FM - 1);
        const bool vy = (ysv >= 0.0f) && (ysv <= Hm1);

        #pragma unroll
        for (int b = 0; b < 2; ++b) {
            const float xsv = xbase + (float)(ix0 + b) * xstep;
            const float x0f = floorf(xsv);
            const float lx  = xsv - x0f;
            int x0 = (int)x0f;
            x0 = min(max(x0, 0), W_FM - 1);
            const int x1c = min(x0 + 1, W_FM - 1);
            const bool vx = (xsv >= 0.0f) && (xsv <= Wm1);

            float4 val;
            if (vy && vx) {   // block-uniform branch, no divergence
                const float4 v00 = *(const float4*)(fmc + ((size_t)y0  * W_FM + x0 ) * C_FM);
                const float4 v01 = *(const float4*)(fmc + ((size_t)y0  * W_FM + x1c) * C_FM);
                const float4 v10 = *(const float4*)(fmc + ((size_t)y1c * W_FM + x0 ) * C_FM);
                const float4 v11 = *(const float4*)(fmc + ((size_t)y1c * W_FM + x1c) * C_FM);

                // top = v00 + (v01 - v00)*lx ; bot = v10 + (v11 - v10)*lx ;
                // val = top + (bot - top)*ly   (reference op order)
                float4 top, bot;
                top.x = v00.x + (v01.x - v00.x) * lx;
                top.y = v00.y + (v01.y - v00.y) * lx;
                top.z = v00.z + (v01.z - v00.z) * lx;
                top.w = v00.w + (v01.w - v00.w) * lx;
                bot.x = v10.x + (v11.x - v10.x) * lx;
                bot.y = v10.y + (v11.y - v10.y) * lx;
                bot.z = v10.z + (v11.z - v10.z) * lx;
                bot.w = v10.w + (v11.w - v10.w) * lx;
                val.x = top.x + (bot.x - top.x) * ly;
                val.y = top.y + (bot.y - top.y) * ly;
                val.z = top.z + (bot.z - top.z) * ly;
                val.w = top.w + (bot.w - top.w) * ly;
            } else {
                val = make_float4(0.0f, 0.0f, 0.0f, 0.0f);
            }

            result.x = fmaxf(result.x, val.x);
            result.y = fmaxf(result.y, val.y);
            result.z = fmaxf(result.z, val.z);
            result.w = fmaxf(result.w, val.w);
        }
    }

    float4* outp = (float4*)(out + ((size_t)bid * C_FM + (size_t)tid * 4));
    *outp = result;
}

extern "C" void kernel_launch(void* const* d_in, const int* in_sizes, int n_in,
                              void* d_out, int out_size, void* d_ws, size_t ws_size,
                              hipStream_t stream) {
    const float* fm        = (const float*)d_in[0];  // [1,200,304,256] f32
    const float* proposals = (const float*)d_in[1];  // [N,4] f32
    const int*   imshape   = (const int*)d_in[2];    // [2] i32
    float* out = (float*)d_out;                      // [N,7,7,256] f32

    const int N = in_sizes[1] / 4;                   // 2000
    dim3 grid((unsigned)(N * PH * PH));              // 98000 blocks
    roi_pool_kernel<<<grid, 64, 0, stream>>>(fm, proposals, imshape, out, N);
}

// Round 4
// 288.577 us; speedup vs baseline: 1.0755x; 1.0755x over previous
//
#include <hip/hip_runtime.h>
#include <math.h>

#define H_FM 200
#define W_FM 304
#define C_FM 256
#define CROP 14
#define PH 7
#define NPOS 49          // 7*7
#define SLABS 16
#define SLAB_C 16        // channels per slab; slab = 200*304*16*4B = 3.9 MB -> fits one XCD 4MB L2

typedef float floatx4 __attribute__((ext_vector_type(4)));  // clang vector: valid for nontemporal builtin

// Block = 256 threads handles one (ROI n, channel-slab) pair.
// Lane decomposition: tid = pgrp*16 + s*4 + q
//   pgrp (0..15): output position within the iteration
//   s    (0..3) : bilinear sub-sample (a = s>>1, b = s&1) of the 2x2 max window
//   q    (0..3) : channel quad -> float4 of channels c0+4q .. c0+4q+3
// Each lane loads its sample's 4 bilinear neighbors (float4 each), computes the
// bilinear value for its 4 channels, then max-reduces across the 4 samples via
// __shfl_xor(4) / __shfl_xor(8). Lanes with s==0 store 16B (4 lanes -> 64B/pos).
//
// XCD pinning: blockIdx -> XCD is round-robin (bid % 8 heuristic). We map
//   xcd  = bid & 7 ; j = bid >> 3 ; phase = j / N ; n = j % N ; slab = phase*8 + xcd
// so XCD x streams slab x across all N ROIs, then slab x+8. The 3.9 MB slab
// stays resident in that XCD's L2 for the whole phase.
__global__ __launch_bounds__(256) void roi_pool_slab_kernel(
    const float* __restrict__ fm,          // [200, 304, 256]
    const float* __restrict__ proposals,   // [N, 4] (x1, y1, x2, y2) image coords
    const int*   __restrict__ image_shape, // [2] (H_img, W_img)
    float*       __restrict__ out,         // [N, 7, 7, 256]
    int N)
{
    const int bid   = blockIdx.x;
    const int xcd   = bid & 7;
    const int j     = bid >> 3;        // 0 .. 2N-1
    const int phase = j / N;           // 0 or 1
    const int n     = j - phase * N;   // ROI index
    const int slab  = phase * 8 + xcd; // 0..15
    const int c0    = slab * SLAB_C;

    const int tid  = threadIdx.x;
    const int pgrp = tid >> 4;         // 0..15
    const int sub  = tid & 15;
    const int s    = sub >> 2;         // sample 0..3
    const int a    = s >> 1;           // y sub-offset
    const int b    = s & 1;            // x sub-offset
    const int q    = sub & 3;          // channel quad

    const float himg = (float)image_shape[0];
    const float wimg = (float)image_shape[1];

    // n is block-uniform -> these become scalar loads
    const float bx1 = proposals[n * 4 + 0] / wimg;
    const float by1 = proposals[n * 4 + 1] / himg;
    const float bx2 = proposals[n * 4 + 2] / wimg;
    const float by2 = proposals[n * 4 + 3] / himg;

    const float Hm1 = (float)(H_FM - 1);
    const float Wm1 = (float)(W_FM - 1);

    // Matches reference: ys = y1*(H-1) + i * ((y2-y1)*(H-1)/(crop-1))
    const float ybase = by1 * Hm1;
    const float xbase = bx1 * Wm1;
    const float ystep = (by2 - by1) * Hm1 / (float)(CROP - 1);
    const float xstep = (bx2 - bx1) * Wm1 / (float)(CROP - 1);

    const float* fmq = fm + c0 + q * 4;  // this lane's channel quad base

    #pragma unroll
    for (int it = 0; it < 4; ++it) {
        const int p = it * 16 + pgrp;            // output position 0..63 (49 valid)
        const bool active = (p < NPOS);

        float vx_ = 0.0f, vy_ = 0.0f, vz_ = 0.0f, vw_ = 0.0f;

        if (active) {
            const int py = p / PH;
            const int px = p - py * PH;

            const float ysv = ybase + (float)(2 * py + a) * ystep;
            const float xsv = xbase + (float)(2 * px + b) * xstep;

            const float y0f = floorf(ysv);
            const float ly  = ysv - y0f;
            int y0 = (int)y0f;
            y0 = min(max(y0, 0), H_FM - 1);
            const int y1c = min(y0 + 1, H_FM - 1);

            const float x0f = floorf(xsv);
            const float lx  = xsv - x0f;
            int x0 = (int)x0f;
            x0 = min(max(x0, 0), W_FM - 1);
            const int x1c = min(x0 + 1, W_FM - 1);

            const bool valid = (ysv >= 0.0f) && (ysv <= Hm1) &&
                               (xsv >= 0.0f) && (xsv <= Wm1);

            if (valid) {
                const float4 v00 = *(const float4*)(fmq + ((size_t)y0  * W_FM + x0 ) * C_FM);
                const float4 v01 = *(const float4*)(fmq + ((size_t)y0  * W_FM + x1c) * C_FM);
                const float4 v10 = *(const float4*)(fmq + ((size_t)y1c * W_FM + x0 ) * C_FM);
                const float4 v11 = *(const float4*)(fmq + ((size_t)y1c * W_FM + x1c) * C_FM);

                // reference op order: top = v00 + (v01-v00)*lx, etc.
                float tx, ty, tz, tw, bx, by, bz, bw;
                tx = v00.x + (v01.x - v00.x) * lx;
                ty = v00.y + (v01.y - v00.y) * lx;
                tz = v00.z + (v01.z - v00.z) * lx;
                tw = v00.w + (v01.w - v00.w) * lx;
                bx = v10.x + (v11.x - v10.x) * lx;
                by = v10.y + (v11.y - v10.y) * lx;
                bz = v10.z + (v11.z - v10.z) * lx;
                bw = v10.w + (v11.w - v10.w) * lx;
                vx_ = tx + (bx - tx) * ly;
                vy_ = ty + (by - ty) * ly;
                vz_ = tz + (bz - tz) * ly;
                vw_ = tw + (bw - tw) * ly;
            }
        }

        // Max-reduce over the 4 samples: partners are lanes tid^4, tid^8
        // (same pgrp, same q). All lanes execute the shuffles.
        vx_ = fmaxf(vx_, __shfl_xor(vx_, 4));
        vy_ = fmaxf(vy_, __shfl_xor(vy_, 4));
        vz_ = fmaxf(vz_, __shfl_xor(vz_, 4));
        vw_ = fmaxf(vw_, __shfl_xor(vw_, 4));
        vx_ = fmaxf(vx_, __shfl_xor(vx_, 8));
        vy_ = fmaxf(vy_, __shfl_xor(vy_, 8));
        vz_ = fmaxf(vz_, __shfl_xor(vz_, 8));
        vw_ = fmaxf(vw_, __shfl_xor(vw_, 8));

        if (active && s == 0) {
            floatx4 v;
            v.x = vx_; v.y = vy_; v.z = vz_; v.w = vw_;
            floatx4* outp = (floatx4*)(out + ((size_t)n * NPOS + p) * C_FM + c0 + q * 4);
            // non-temporal: keep the 98 MB output stream from evicting the L2-resident slab
            __builtin_nontemporal_store(v, outp);
        }
    }
}

extern "C" void kernel_launch(void* const* d_in, const int* in_sizes, int n_in,
                              void* d_out, int out_size, void* d_ws, size_t ws_size,
                              hipStream_t stream) {
    const float* fm        = (const float*)d_in[0];  // [1,200,304,256] f32
    const float* proposals = (const float*)d_in[1];  // [N,4] f32
    const int*   imshape   = (const int*)d_in[2];    // [2] i32
    float* out = (float*)d_out;                      // [N,7,7,256] f32

    const int N = in_sizes[1] / 4;                   // 2000
    dim3 grid((unsigned)(SLABS * N));                // 32000 blocks
    roi_pool_slab_kernel<<<grid, 256, 0, stream>>>(fm, proposals, imshape, out, N);
}

// Round 5
// 221.605 us; speedup vs baseline: 1.4006x; 1.3022x over previous
//
#include <hip/hip_runtime.h>
#include <math.h>

#define H_FM 200
#define W_FM 304
#define C_FM 256
#define NPIX (H_FM * W_FM)           // 60800
#define CROP 14
#define PH 7
#define NPOS 49                       // 7*7
#define SLABS 16
#define SLAB_C 16                     // channels per slab
#define SLAB_ELEMS (NPIX * SLAB_C)    // 972800 floats = 3.89 MB contiguous -> dense in one XCD L2

typedef float floatx4 __attribute__((ext_vector_type(4)));

// Repack [H,W,256] -> 16 contiguous slabs of [H,W,16].
// One wave = one pixel: reads 1 KB fully coalesced, writes 64 B to each of the
// 16 slabs. Consecutive waves -> consecutive pixels -> consecutive 64 B per
// slab, so the write stream is dense per slab region too.
__global__ __launch_bounds__(256) void repack_kernel(
    const float* __restrict__ fm,      // [NPIX, 256]
    float*       __restrict__ slabbed) // [16][NPIX][16]
{
    const int idx = blockIdx.x * 256 + threadIdx.x;  // float4 index in source order
    const int p   = idx >> 6;                        // pixel
    const int c4  = idx & 63;                        // channel quad 0..63
    const int s   = c4 >> 2;                         // slab
    const int cq  = c4 & 3;                          // quad within slab
    const float4 v = *(const float4*)(fm + (size_t)idx * 4);
    *(float4*)(slabbed + (size_t)s * SLAB_ELEMS + (size_t)p * SLAB_C + cq * 4) = v;
}

// Block = 256 threads handles one (ROI n, channel-slab) pair, reading the
// DENSE slab (fixes the L2 set-index pathology of the strided layout: the
// strided slab touched 64B of every 1KB so it used ~1/8 of L2 sets ->
// effective capacity ~0.5MB -> thrash; dense slab uses all sets).
// Lane decomposition: tid = pgrp*16 + s*4 + q (see R2 notes).
// XCD pinning: xcd = bid & 7; XCD x streams slab x for all N ROIs, then x+8.
template <bool SLABBED>
__global__ __launch_bounds__(256) void roi_pool_slab_kernel(
    const float* __restrict__ fmbase,      // SLABBED ? [16][NPIX][16] : [NPIX,256]
    const float* __restrict__ proposals,   // [N, 4] (x1, y1, x2, y2) image coords
    const int*   __restrict__ image_shape, // [2] (H_img, W_img)
    float*       __restrict__ out,         // [N, 7, 7, 256]
    int N)
{
    const int bid   = blockIdx.x;
    const int xcd   = bid & 7;
    const int j     = bid >> 3;        // 0 .. 2N-1
    const int phase = j / N;           // 0 or 1
    const int n     = j - phase * N;   // ROI index
    const int slab  = phase * 8 + xcd; // 0..15
    const int c0    = slab * SLAB_C;

    const int tid  = threadIdx.x;
    const int pgrp = tid >> 4;         // 0..15
    const int sub  = tid & 15;
    const int s    = sub >> 2;         // sample 0..3
    const int a    = s >> 1;           // y sub-offset
    const int b    = s & 1;            // x sub-offset
    const int q    = sub & 3;          // channel quad

    const float himg = (float)image_shape[0];
    const float wimg = (float)image_shape[1];

    const float bx1 = proposals[n * 4 + 0] / wimg;
    const float by1 = proposals[n * 4 + 1] / himg;
    const float bx2 = proposals[n * 4 + 2] / wimg;
    const float by2 = proposals[n * 4 + 3] / himg;

    const float Hm1 = (float)(H_FM - 1);
    const float Wm1 = (float)(W_FM - 1);

    // Matches reference: ys = y1*(H-1) + i * ((y2-y1)*(H-1)/(crop-1))
    const float ybase = by1 * Hm1;
    const float xbase = bx1 * Wm1;
    const float ystep = (by2 - by1) * Hm1 / (float)(CROP - 1);
    const float xstep = (bx2 - bx1) * Wm1 / (float)(CROP - 1);

    // this lane's channel-quad base and pixel stride in the active layout
    const float* fmq = SLABBED
        ? fmbase + (size_t)slab * SLAB_ELEMS + q * 4
        : fmbase + c0 + q * 4;
    const int PIX_STRIDE = SLABBED ? SLAB_C : C_FM;

    #pragma unroll
    for (int it = 0; it < 4; ++it) {
        const int p = it * 16 + pgrp;            // output position 0..63 (49 valid)
        const bool active = (p < NPOS);

        float vx_ = 0.0f, vy_ = 0.0f, vz_ = 0.0f, vw_ = 0.0f;

        if (active) {
            const int py = p / PH;
            const int px = p - py * PH;

            const float ysv = ybase + (float)(2 * py + a) * ystep;
            const float xsv = xbase + (float)(2 * px + b) * xstep;

            const float y0f = floorf(ysv);
            const float ly  = ysv - y0f;
            int y0 = (int)y0f;
            y0 = min(max(y0, 0), H_FM - 1);
            const int y1c = min(y0 + 1, H_FM - 1);

            const float x0f = floorf(xsv);
            const float lx  = xsv - x0f;
            int x0 = (int)x0f;
            x0 = min(max(x0, 0), W_FM - 1);
            const int x1c = min(x0 + 1, W_FM - 1);

            const bool valid = (ysv >= 0.0f) && (ysv <= Hm1) &&
                               (xsv >= 0.0f) && (xsv <= Wm1);

            if (valid) {
                const float4 v00 = *(const float4*)(fmq + (size_t)(y0  * W_FM + x0 ) * PIX_STRIDE);
                const float4 v01 = *(const float4*)(fmq + (size_t)(y0  * W_FM + x1c) * PIX_STRIDE);
                const float4 v10 = *(const float4*)(fmq + (size_t)(y1c * W_FM + x0 ) * PIX_STRIDE);
                const float4 v11 = *(const float4*)(fmq + (size_t)(y1c * W_FM + x1c) * PIX_STRIDE);

                // reference op order: top = v00 + (v01-v00)*lx, etc.
                float tx, ty, tz, tw, bx, by, bz, bw;
                tx = v00.x + (v01.x - v00.x) * lx;
                ty = v00.y + (v01.y - v00.y) * lx;
                tz = v00.z + (v01.z - v00.z) * lx;
                tw = v00.w + (v01.w - v00.w) * lx;
                bx = v10.x + (v11.x - v10.x) * lx;
                by = v10.y + (v11.y - v10.y) * lx;
                bz = v10.z + (v11.z - v10.z) * lx;
                bw = v10.w + (v11.w - v10.w) * lx;
                vx_ = tx + (bx - tx) * ly;
                vy_ = ty + (by - ty) * ly;
                vz_ = tz + (bz - tz) * ly;
                vw_ = tw + (bw - tw) * ly;
            }
        }

        // Max-reduce over the 4 samples: partners are lanes tid^4, tid^8.
        vx_ = fmaxf(vx_, __shfl_xor(vx_, 4));
        vy_ = fmaxf(vy_, __shfl_xor(vy_, 4));
        vz_ = fmaxf(vz_, __shfl_xor(vz_, 4));
        vw_ = fmaxf(vw_, __shfl_xor(vw_, 4));
        vx_ = fmaxf(vx_, __shfl_xor(vx_, 8));
        vy_ = fmaxf(vy_, __shfl_xor(vy_, 8));
        vz_ = fmaxf(vz_, __shfl_xor(vz_, 8));
        vw_ = fmaxf(vw_, __shfl_xor(vw_, 8));

        if (active && s == 0) {
            floatx4 v;
            v.x = vx_; v.y = vy_; v.z = vz_; v.w = vw_;
            floatx4* outp = (floatx4*)(out + ((size_t)n * NPOS + p) * C_FM + c0 + q * 4);
            // non-temporal: keep the 98 MB output stream from evicting the slab
            __builtin_nontemporal_store(v, outp);
        }
    }
}

extern "C" void kernel_launch(void* const* d_in, const int* in_sizes, int n_in,
                              void* d_out, int out_size, void* d_ws, size_t ws_size,
                              hipStream_t stream) {
    const float* fm        = (const float*)d_in[0];  // [1,200,304,256] f32
    const float* proposals = (const float*)d_in[1];  // [N,4] f32
    const int*   imshape   = (const int*)d_in[2];    // [2] i32
    float* out = (float*)d_out;                      // [N,7,7,256] f32

    const int N = in_sizes[1] / 4;                   // 2000
    const size_t needed = (size_t)SLABS * SLAB_ELEMS * sizeof(float); // 62.3 MB

    if (ws_size >= needed) {
        // total float4s in fm = NPIX*64; 256 thr/block -> NPIX/4 blocks
        repack_kernel<<<NPIX / 4, 256, 0, stream>>>(fm, (float*)d_ws);
        roi_pool_slab_kernel<true><<<SLABS * N, 256, 0, stream>>>(
            (const float*)d_ws, proposals, imshape, out, N);
    } else {
        // fallback: direct strided read (R4 behavior)
        roi_pool_slab_kernel<false><<<SLABS * N, 256, 0, stream>>>(
            fm, proposals, imshape, out, N);
    }
}